// Round 2
// baseline (97.276 us; speedup 1.0000x reference)
//
#include <hip/hip_runtime.h>

#define NF 13          // y = [1, x1..x12]
#define NEXP 454       // unique monomials
#define NROWS 65536
#define BN_EPS 1e-5f

// Decode feature index j (0..453) -> nondecreasing triple (i0<=i1<=i2),
// lexicographic order over (i0,i1,i2), skipping (0,0,0).
__device__ __forceinline__ void decode_triple(int j, int& i0, int& i1, int& i2) {
    int g = j + 1;  // global rank among all 455 nondecreasing triples
    i0 = 0;
    for (;;) {
        int m = NF - i0;
        int c = m * (m + 1) / 2;     // triples with this i0
        if (g < c) break;
        g -= c; ++i0;
    }
    i1 = i0;
    for (;;) {
        int m = NF - i1;             // triples with this (i0,i1)
        if (g < m) break;
        g -= m; ++i1;
    }
    i2 = i1 + g;
}

// ---------------- Pass 0: zero the accumulators (replaces hipMemsetAsync) ---
__global__ __launch_bounds__(1024) void zero_ws_kernel(float* __restrict__ ws) {
    int t = threadIdx.x;
    if (t < 2 * NEXP) ws[t] = 0.0f;
}

// ---------------- Pass 1: per-feature sum and sum-of-squares ----------------
template <int ROWS>
__global__ __launch_bounds__(256) void stats_kernel(const float* __restrict__ x,
                                                    float* __restrict__ sums) {
    __shared__ float y[ROWS][NF];
    const int tid = threadIdx.x;
    const int row0 = blockIdx.x * ROWS;

    // Stage x chunk -> LDS as y rows (coalesced: contiguous 12*ROWS floats)
    for (int idx = tid; idx < ROWS * 12; idx += 256) {
        int r = idx / 12, c = idx - r * 12;
        y[r][c + 1] = x[(size_t)row0 * 12 + idx];
    }
    for (int r = tid; r < ROWS; r += 256) y[r][0] = 1.0f;
    __syncthreads();

    const int j0 = tid;            // always < 454 since blockDim=256
    const int j1 = tid + 256;
    const bool has1 = (j1 < NEXP);
    int a0, a1, a2, b0 = 0, b1 = 0, b2 = 0;
    decode_triple(j0, a0, a1, a2);
    if (has1) decode_triple(j1, b0, b1, b2);

    float s0 = 0.f, q0 = 0.f, s1 = 0.f, q1 = 0.f;
    #pragma unroll 4
    for (int r = 0; r < ROWS; ++r) {
        float f0 = y[r][a0] * y[r][a1] * y[r][a2];
        s0 += f0; q0 += f0 * f0;
        if (has1) {
            float f1 = y[r][b0] * y[r][b1] * y[r][b2];
            s1 += f1; q1 += f1 * f1;
        }
    }
    atomicAdd(&sums[j0], s0);
    atomicAdd(&sums[NEXP + j0], q0);
    if (has1) {
        atomicAdd(&sums[j1], s1);
        atomicAdd(&sums[NEXP + j1], q1);
    }
}

// ---------------- Pass 2: fold BN stats into scale/shift --------------------
__global__ __launch_bounds__(256) void finalize_kernel(const float* __restrict__ sums,
                                                       const float* __restrict__ w,
                                                       const float* __restrict__ b,
                                                       float* __restrict__ ss) {
    int j = blockIdx.x * 256 + threadIdx.x;
    if (j >= NEXP) return;
    const float inv_n = 1.0f / (float)NROWS;
    float mean = sums[j] * inv_n;
    float var  = sums[NEXP + j] * inv_n - mean * mean;
    float scale = rsqrtf(var + BN_EPS) * w[j];
    ss[j] = scale;
    ss[NEXP + j] = b[j] - mean * scale;
}

// ---------------- Pass 3: recompute feats, apply affine, store --------------
template <int ROWS>
__global__ __launch_bounds__(256) void write_kernel(const float* __restrict__ x,
                                                    const float* __restrict__ ss,
                                                    float* __restrict__ out) {
    __shared__ float y[ROWS][NF];
    const int tid = threadIdx.x;
    const int row0 = blockIdx.x * ROWS;

    for (int idx = tid; idx < ROWS * 12; idx += 256) {
        int r = idx / 12, c = idx - r * 12;
        y[r][c + 1] = x[(size_t)row0 * 12 + idx];
    }
    for (int r = tid; r < ROWS; r += 256) y[r][0] = 1.0f;

    const int j0 = tid;
    const int j1 = tid + 256;
    const bool has1 = (j1 < NEXP);
    int a0, a1, a2, b0 = 0, b1 = 0, b2 = 0;
    decode_triple(j0, a0, a1, a2);
    if (has1) decode_triple(j1, b0, b1, b2);
    // scale/shift are tiny (3.6 KB) and L2-resident -> read directly.
    const float sc0 = ss[j0], sh0 = ss[NEXP + j0];
    const float sc1 = has1 ? ss[j1] : 0.f, sh1 = has1 ? ss[NEXP + j1] : 0.f;
    __syncthreads();

    for (int r = 0; r < ROWS; ++r) {
        float* o = out + (size_t)(row0 + r) * NEXP;
        float f0 = y[r][a0] * y[r][a1] * y[r][a2];
        __builtin_nontemporal_store(f0 * sc0 + sh0, &o[j0]);
        if (has1) {
            float f1 = y[r][b0] * y[r][b1] * y[r][b2];
            __builtin_nontemporal_store(f1 * sc1 + sh1, &o[j1]);
        }
    }
}

extern "C" void kernel_launch(void* const* d_in, const int* in_sizes, int n_in,
                              void* d_out, int out_size, void* d_ws, size_t ws_size,
                              hipStream_t stream) {
    const float* x  = (const float*)d_in[0];
    const float* bw = (const float*)d_in[1];
    const float* bb = (const float*)d_in[2];
    float* out = (float*)d_out;
    float* ws  = (float*)d_ws;   // [0..907]=sum,sumsq  [908..1815]=scale,shift

    // Zero the accumulators every call with our own kernel (graph-captured
    // hipMemsetAsync / rocclr fillBufferAligned measured ~70us per replay).
    zero_ws_kernel<<<1, 1024, 0, stream>>>(ws);

    constexpr int SROWS = 64;
    stats_kernel<SROWS><<<NROWS / SROWS, 256, 0, stream>>>(x, ws);

    finalize_kernel<<<2, 256, 0, stream>>>(ws, bw, bb, ws + 2 * NEXP);

    constexpr int WROWS = 32;
    write_kernel<WROWS><<<NROWS / WROWS, 256, 0, stream>>>(x, ws + 2 * NEXP, out);
}

// Round 3
// 68.160 us; speedup vs baseline: 1.4272x; 1.4272x over previous
//
#include <hip/hip_runtime.h>

#define NF 13          // y = [1, x1..x12]
#define NEXP 454       // unique monomials
#define NROWS 65536
#define BN_EPS 1e-5f
#define SBLK 512       // stats blocks
#define SROWS (NROWS / SBLK)   // 128 rows per stats block
#define PARTW 908      // per-block partial row: [454 sums | 454 sumsqs]

// Decode feature index j (0..453) -> nondecreasing triple (i0<=i1<=i2),
// lexicographic order over (i0,i1,i2), skipping (0,0,0).
__device__ __forceinline__ void decode_triple(int j, int& i0, int& i1, int& i2) {
    int g = j + 1;  // global rank among all 455 nondecreasing triples
    i0 = 0;
    for (;;) {
        int m = NF - i0;
        int c = m * (m + 1) / 2;     // triples with this i0
        if (g < c) break;
        g -= c; ++i0;
    }
    i1 = i0;
    for (;;) {
        int m = NF - i1;             // triples with this (i0,i1)
        if (g < m) break;
        g -= m; ++i1;
    }
    i2 = i1 + g;
}

// ---------------- Pass 1: per-block partial sum / sumsq (no atomics) --------
__global__ __launch_bounds__(256) void stats_kernel(const float* __restrict__ x,
                                                    float* __restrict__ part) {
    __shared__ float y[SROWS][NF];
    const int tid = threadIdx.x;
    const int row0 = blockIdx.x * SROWS;

    // Stage x chunk -> LDS rows (coalesced contiguous read of 12*SROWS floats)
    for (int idx = tid; idx < SROWS * 12; idx += 256) {
        int r = idx / 12, c = idx - r * 12;
        y[r][c + 1] = x[(size_t)row0 * 12 + idx];
    }
    for (int r = tid; r < SROWS; r += 256) y[r][0] = 1.0f;
    __syncthreads();

    const int j0 = tid;
    const int j1 = tid + 256;
    const bool has1 = (j1 < NEXP);
    int a0, a1, a2, b0 = 0, b1 = 0, b2 = 0;
    decode_triple(j0, a0, a1, a2);
    if (has1) decode_triple(j1, b0, b1, b2);

    float s0 = 0.f, q0 = 0.f, s1 = 0.f, q1 = 0.f;
    #pragma unroll 4
    for (int r = 0; r < SROWS; ++r) {
        float f0 = y[r][a0] * y[r][a1] * y[r][a2];
        s0 += f0; q0 += f0 * f0;
        if (has1) {
            float f1 = y[r][b0] * y[r][b1] * y[r][b2];
            s1 += f1; q1 += f1 * f1;
        }
    }
    float* p = part + (size_t)blockIdx.x * PARTW;
    p[j0] = s0;
    p[NEXP + j0] = q0;
    if (has1) {
        p[j1] = s1;
        p[NEXP + j1] = q1;
    }
}

// ---------------- Pass 2: reduce partials, fold BN into scale/shift ---------
__global__ __launch_bounds__(128) void finalize_kernel(const float* __restrict__ part,
                                                       const float* __restrict__ w,
                                                       const float* __restrict__ b,
                                                       float* __restrict__ ss) {
    int j = blockIdx.x * 128 + threadIdx.x;
    if (j >= NEXP) return;
    float s = 0.f, q = 0.f;
    #pragma unroll 8
    for (int blk = 0; blk < SBLK; ++blk) {
        s += part[(size_t)blk * PARTW + j];          // coalesced across threads
        q += part[(size_t)blk * PARTW + NEXP + j];
    }
    const float inv_n = 1.0f / (float)NROWS;
    float mean = s * inv_n;
    float var  = q * inv_n - mean * mean;
    float scale = rsqrtf(var + BN_EPS) * w[j];
    ss[j] = scale;
    ss[NEXP + j] = b[j] - mean * scale;
}

// ---------------- Pass 3: recompute feats, apply affine, store --------------
template <int ROWS>
__global__ __launch_bounds__(256) void write_kernel(const float* __restrict__ x,
                                                    const float* __restrict__ ss,
                                                    float* __restrict__ out) {
    __shared__ float y[ROWS][NF];
    const int tid = threadIdx.x;
    const int row0 = blockIdx.x * ROWS;

    for (int idx = tid; idx < ROWS * 12; idx += 256) {
        int r = idx / 12, c = idx - r * 12;
        y[r][c + 1] = x[(size_t)row0 * 12 + idx];
    }
    for (int r = tid; r < ROWS; r += 256) y[r][0] = 1.0f;

    const int j0 = tid;
    const int j1 = tid + 256;
    const bool has1 = (j1 < NEXP);
    int a0, a1, a2, b0 = 0, b1 = 0, b2 = 0;
    decode_triple(j0, a0, a1, a2);
    if (has1) decode_triple(j1, b0, b1, b2);
    // scale/shift are tiny (3.6 KB), L2-resident -> read directly.
    const float sc0 = ss[j0], sh0 = ss[NEXP + j0];
    const float sc1 = has1 ? ss[j1] : 0.f, sh1 = has1 ? ss[NEXP + j1] : 0.f;
    __syncthreads();

    for (int r = 0; r < ROWS; ++r) {
        float* o = out + (size_t)(row0 + r) * NEXP;
        float f0 = y[r][a0] * y[r][a1] * y[r][a2];
        o[j0] = f0 * sc0 + sh0;                      // plain stores: let L2
        if (has1) {                                  // merge partial lines
            float f1 = y[r][b0] * y[r][b1] * y[r][b2];
            o[j1] = f1 * sc1 + sh1;
        }
    }
}

extern "C" void kernel_launch(void* const* d_in, const int* in_sizes, int n_in,
                              void* d_out, int out_size, void* d_ws, size_t ws_size,
                              hipStream_t stream) {
    const float* x  = (const float*)d_in[0];
    const float* bw = (const float*)d_in[1];
    const float* bb = (const float*)d_in[2];
    float* out  = (float*)d_out;
    float* part = (float*)d_ws;                    // SBLK*908 floats = 1.86 MB
    float* ss   = part + (size_t)SBLK * PARTW;     // 908 floats scale/shift

    stats_kernel<<<SBLK, 256, 0, stream>>>(x, part);
    finalize_kernel<<<4, 128, 0, stream>>>(part, bw, bb, ss);
    constexpr int WROWS = 16;
    write_kernel<WROWS><<<NROWS / WROWS, 256, 0, stream>>>(x, ss, out);
}

// Round 4
// 44.958 us; speedup vs baseline: 2.1637x; 1.5161x over previous
//
#include <hip/hip_runtime.h>

#define NF 13          // y = [1, x1..x12]
#define NEXP 454       // unique monomials
#define NROWS 65536
#define BN_EPS 1e-5f
#define SBLK 512               // stats blocks
#define SROWS (NROWS / SBLK)   // 128 rows per stats block
#define PARTW 908              // per-block partial row: [454 sums | 454 sumsqs]
#define SPAD (SROWS + 4)       // padded column stride (words): 132, 16B-aligned,
                               // 132 mod 32 = 4 -> columns spread across banks
#define WROWS 64               // rows per write block
#define WPAD (WROWS + 4)       // 68 words: 16B-aligned, 68 mod 32 = 4

// Decode feature index j (0..453) -> nondecreasing triple (i0<=i1<=i2),
// lexicographic order over (i0,i1,i2), skipping (0,0,0).
__device__ __forceinline__ void decode_triple(int j, int& i0, int& i1, int& i2) {
    int g = j + 1;
    i0 = 0;
    for (;;) {
        int m = NF - i0;
        int c = m * (m + 1) / 2;
        if (g < c) break;
        g -= c; ++i0;
    }
    i1 = i0;
    for (;;) {
        int m = NF - i1;
        if (g < m) break;
        g -= m; ++i1;
    }
    i2 = i1 + g;
}

// ---------------- Pass 1: per-block partial sum / sumsq (no atomics) --------
// Column-major LDS + 4-rows-per-iter float4 reads -> ds_read_b128.
__global__ __launch_bounds__(256) void stats_kernel(const float* __restrict__ x,
                                                    float* __restrict__ part) {
    __shared__ float yc[NF][SPAD];
    const int tid = threadIdx.x;
    const int row0 = blockIdx.x * SROWS;

    for (int idx = tid; idx < SROWS * 12; idx += 256) {
        int r = idx / 12, c = idx - r * 12;
        yc[c + 1][r] = x[(size_t)row0 * 12 + idx];
    }
    for (int r = tid; r < SROWS; r += 256) yc[0][r] = 1.0f;
    __syncthreads();

    const int j0 = tid;
    const int j1 = tid + 256;
    const bool has1 = (j1 < NEXP);
    int a0, a1, a2, b0 = 0, b1 = 0, b2 = 0;
    decode_triple(j0, a0, a1, a2);
    if (has1) decode_triple(j1, b0, b1, b2);

    float s0 = 0.f, q0 = 0.f, s1 = 0.f, q1 = 0.f;
    for (int r = 0; r < SROWS; r += 4) {
        float4 va = *reinterpret_cast<const float4*>(&yc[a0][r]);
        float4 vb = *reinterpret_cast<const float4*>(&yc[a1][r]);
        float4 vc = *reinterpret_cast<const float4*>(&yc[a2][r]);
        float f;
        f = va.x * vb.x * vc.x; s0 += f; q0 += f * f;
        f = va.y * vb.y * vc.y; s0 += f; q0 += f * f;
        f = va.z * vb.z * vc.z; s0 += f; q0 += f * f;
        f = va.w * vb.w * vc.w; s0 += f; q0 += f * f;
        if (has1) {
            float4 wa = *reinterpret_cast<const float4*>(&yc[b0][r]);
            float4 wb = *reinterpret_cast<const float4*>(&yc[b1][r]);
            float4 wc = *reinterpret_cast<const float4*>(&yc[b2][r]);
            f = wa.x * wb.x * wc.x; s1 += f; q1 += f * f;
            f = wa.y * wb.y * wc.y; s1 += f; q1 += f * f;
            f = wa.z * wb.z * wc.z; s1 += f; q1 += f * f;
            f = wa.w * wb.w * wc.w; s1 += f; q1 += f * f;
        }
    }
    float* p = part + (size_t)blockIdx.x * PARTW;
    p[j0] = s0;
    p[NEXP + j0] = q0;
    if (has1) {
        p[j1] = s1;
        p[NEXP + j1] = q1;
    }
}

// ---------------- Pass 2: reduce partials, fold BN into scale/shift ---------
// 8-way slice parallelism per feature: 454*8 threads, coalesced loads.
#define FIN_FPB 32   // features per block
__global__ __launch_bounds__(256) void finalize_kernel(const float* __restrict__ part,
                                                       const float* __restrict__ w,
                                                       const float* __restrict__ b,
                                                       float* __restrict__ ss) {
    __shared__ float reds[8][FIN_FPB];
    __shared__ float redq[8][FIN_FPB];
    const int fl = threadIdx.x & 31;
    const int k  = threadIdx.x >> 5;              // slice 0..7
    const int f  = blockIdx.x * FIN_FPB + fl;
    float s = 0.f, q = 0.f;
    if (f < NEXP) {
        #pragma unroll 4
        for (int i = 0; i < SBLK / 8; ++i) {
            const float* p = part + (size_t)(k * (SBLK / 8) + i) * PARTW;
            s += p[f];
            q += p[NEXP + f];
        }
    }
    reds[k][fl] = s;
    redq[k][fl] = q;
    __syncthreads();
    if (threadIdx.x < FIN_FPB && f < NEXP) {
        float ts = 0.f, tq = 0.f;
        #pragma unroll
        for (int kk = 0; kk < 8; ++kk) { ts += reds[kk][fl]; tq += redq[kk][fl]; }
        const float inv_n = 1.0f / (float)NROWS;
        float mean = ts * inv_n;
        float var  = tq * inv_n - mean * mean;
        float scale = rsqrtf(var + BN_EPS) * w[f];
        ss[f] = scale;
        ss[NEXP + f] = b[f] - mean * scale;
    }
}

// ---------------- Pass 3: recompute feats, apply affine, store --------------
__global__ __launch_bounds__(256) void write_kernel(const float* __restrict__ x,
                                                    const float* __restrict__ ss,
                                                    float* __restrict__ out) {
    __shared__ float yc[NF][WPAD];
    const int tid = threadIdx.x;
    const int row0 = blockIdx.x * WROWS;

    for (int idx = tid; idx < WROWS * 12; idx += 256) {
        int r = idx / 12, c = idx - r * 12;
        yc[c + 1][r] = x[(size_t)row0 * 12 + idx];
    }
    for (int r = tid; r < WROWS; r += 256) yc[0][r] = 1.0f;

    const int j0 = tid;
    const int j1 = tid + 256;
    const bool has1 = (j1 < NEXP);
    int a0, a1, a2, b0 = 0, b1 = 0, b2 = 0;
    decode_triple(j0, a0, a1, a2);
    if (has1) decode_triple(j1, b0, b1, b2);
    const float sc0 = ss[j0], sh0 = ss[NEXP + j0];
    const float sc1 = has1 ? ss[j1] : 0.f, sh1 = has1 ? ss[NEXP + j1] : 0.f;
    __syncthreads();

    for (int r = 0; r < WROWS; r += 4) {
        float4 va = *reinterpret_cast<const float4*>(&yc[a0][r]);
        float4 vb = *reinterpret_cast<const float4*>(&yc[a1][r]);
        float4 vc = *reinterpret_cast<const float4*>(&yc[a2][r]);
        float* o = out + (size_t)(row0 + r) * NEXP + j0;
        o[0 * NEXP] = va.x * vb.x * vc.x * sc0 + sh0;
        o[1 * NEXP] = va.y * vb.y * vc.y * sc0 + sh0;
        o[2 * NEXP] = va.z * vb.z * vc.z * sc0 + sh0;
        o[3 * NEXP] = va.w * vb.w * vc.w * sc0 + sh0;
        if (has1) {
            float4 wa = *reinterpret_cast<const float4*>(&yc[b0][r]);
            float4 wb = *reinterpret_cast<const float4*>(&yc[b1][r]);
            float4 wc = *reinterpret_cast<const float4*>(&yc[b2][r]);
            float* o1 = out + (size_t)(row0 + r) * NEXP + j1;
            o1[0 * NEXP] = wa.x * wb.x * wc.x * sc1 + sh1;
            o1[1 * NEXP] = wa.y * wb.y * wc.y * sc1 + sh1;
            o1[2 * NEXP] = wa.z * wb.z * wc.z * sc1 + sh1;
            o1[3 * NEXP] = wa.w * wb.w * wc.w * sc1 + sh1;
        }
    }
}

extern "C" void kernel_launch(void* const* d_in, const int* in_sizes, int n_in,
                              void* d_out, int out_size, void* d_ws, size_t ws_size,
                              hipStream_t stream) {
    const float* x  = (const float*)d_in[0];
    const float* bw = (const float*)d_in[1];
    const float* bb = (const float*)d_in[2];
    float* out  = (float*)d_out;
    float* part = (float*)d_ws;                    // SBLK*908 floats = 1.86 MB
    float* ss   = part + (size_t)SBLK * PARTW;     // 908 floats scale/shift

    stats_kernel<<<SBLK, 256, 0, stream>>>(x, part);
    finalize_kernel<<<(NEXP + FIN_FPB - 1) / FIN_FPB, 256, 0, stream>>>(part, bw, bb, ss);
    write_kernel<<<NROWS / WROWS, 256, 0, stream>>>(x, ss, out);
}